// Round 12
// baseline (362.012 us; speedup 1.0000x reference)
//
#include <hip/hip_runtime.h>
#include <math.h>

#define NCH 256
#define HH 100
#define WW 152
#define BB 4
#define NROIS 512
#define FDIM 12544   // 256*49
#define DFC 1024
#define HW 15200     // 100*152

typedef unsigned short u16;
typedef float f32x4 __attribute__((ext_vector_type(4)));
typedef short s16x8 __attribute__((ext_vector_type(8)));
typedef __bf16 bf16x8 __attribute__((ext_vector_type(8)));

__device__ __forceinline__ u16 f2bf(float f) {
  union { float f; unsigned u; } c; c.f = f;
  unsigned u = c.u;
  return (u16)((u + 0x7FFFu + ((u >> 16) & 1u)) >> 16);  // RNE
}
__device__ __forceinline__ float bf2f(u16 h) {
  union { unsigned u; float f; } c; c.u = ((unsigned)h) << 16;
  return c.f;
}

// ---------------- deform roi pool, NCHW fallback (proven) --------------
template<int WITH_OFF>
__global__ __launch_bounds__(256) void pool_nchw(
    const float* __restrict__ feat, const float* __restrict__ rois,
    const float* __restrict__ offp, float* __restrict__ out) {
  const int n    = blockIdx.x;
  const int tid  = threadIdx.x;
  const int wave = tid >> 6;
  const int lane = tid & 63;
  float r[5];
  const float* rp = rois + n * 5;
  #pragma unroll
  for (int i = 0; i < 5; ++i) r[i] = rp[i];
  int b = (int)r[0];
  b = min(max(b, 0), BB - 1);
  const float x1 = r[1] * 0.0625f - 0.5f;
  const float y1 = r[2] * 0.0625f - 0.5f;
  const float x2 = r[3] * 0.0625f - 0.5f;
  const float y2 = r[4] * 0.0625f - 0.5f;
  const float rw = x2 - x1, rh = y2 - y1;
  const float bw = rw * (1.0f / 7.0f), bh = rh * (1.0f / 7.0f);
  const int bin = lane;
  const bool active = (bin < 49);
  const int ph = bin / 7;
  const int pw = bin - ph * 7;
  float sw = x1, sh = y1;
  if (WITH_OFF && active) {
    sw += 0.1f * rw * offp[n * 98 + bin];
    sh += 0.1f * rh * offp[n * 98 + 49 + bin];
  }
  int idx[4];
  float wt[4][4];
  bool val[4];
  #pragma unroll
  for (int s = 0; s < 4; ++s) {
    const int i = s >> 1, j = s & 1;
    const float y = sh + ((float)ph + 0.25f + 0.5f * (float)i) * bh;
    const float x = sw + ((float)pw + 0.25f + 0.5f * (float)j) * bw;
    val[s] = active && (y > -1.0f) && (y < (float)HH) && (x > -1.0f) && (x < (float)WW);
    float yc = fminf(fmaxf(y, 0.f), (float)(HH - 1));
    float xc = fminf(fmaxf(x, 0.f), (float)(WW - 1));
    int y0 = min(max((int)floorf(yc), 0), HH - 2);
    int x0 = min(max((int)floorf(xc), 0), WW - 2);
    const float ly = yc - (float)y0, lx = xc - (float)x0;
    const float hy = 1.f - ly, hx = 1.f - lx;
    idx[s] = y0 * WW + x0;
    wt[s][0] = hy * hx; wt[s][1] = hy * lx;
    wt[s][2] = ly * hx; wt[s][3] = ly * lx;
  }
  const float* fb = feat + (size_t)b * NCH * HW;
  float* op = out + (size_t)n * FDIM;
  for (int c = wave; c < NCH; c += 4) {
    const float* plane = fb + (size_t)c * HW;
    float acc = 0.f;
    #pragma unroll
    for (int s = 0; s < 4; ++s) {
      if (val[s]) {
        const float* p = plane + idx[s];
        acc += wt[s][0] * p[0] + wt[s][1] * p[1]
             + wt[s][2] * p[WW] + wt[s][3] * p[WW + 1];
      }
    }
    if (active) op[c * 49 + bin] = acc * 0.25f;
  }
}

// ------- NCHW -> NHWC transpose (64x64 LDS tile, both sides coalesced) --
__global__ __launch_bounds__(256) void nchw_to_nhwc(
    const float* __restrict__ in, float* __restrict__ outp) {
  __shared__ float tile[64][65];
  const int b  = blockIdx.z;
  const int c0 = blockIdx.y * 64;
  const int p0 = blockIdx.x * 64;
  const int tx = threadIdx.x & 63;
  const int ty = threadIdx.x >> 6;
  const float* ib = in + ((size_t)b * NCH + c0) * HW + p0;
  #pragma unroll
  for (int i = 0; i < 16; ++i) {
    const int r = ty + i * 4;                    // channel row 0..63
    tile[r][tx] = (p0 + tx < HW) ? ib[(size_t)r * HW + tx] : 0.f;
  }
  __syncthreads();
  float* ob = outp + ((size_t)b * HW + p0) * NCH + c0;
  #pragma unroll
  for (int i = 0; i < 16; ++i) {
    const int pr = ty + i * 4;                   // position row 0..63
    if (p0 + pr < HW) ob[(size_t)pr * NCH + tx] = tile[tx][pr];
  }
}

// ------ deform roi pool on NHWC, channel-group split + LDS store -------
// (round-8 proven). SPLIT=1 additionally writes bf16 hi/lo (RNE, identical
// values to what the GEMM would have computed in-loop) for the A operand.
template<int WITH_OFF, int SPLIT>
__global__ __launch_bounds__(256) void pool_nhwc_cg(
    const float* __restrict__ feat, const float* __restrict__ rois,
    const float* __restrict__ offp, float* __restrict__ out,
    u16* __restrict__ ahi, u16* __restrict__ alo) {
  __shared__ float obuf[64 * 49];
  const int n  = blockIdx.x;
  const int cg = blockIdx.y;               // channel group 0..3
  const int w    = threadIdx.x >> 6;       // wave 0..3
  const int lane = threadIdx.x & 63;       // c_local
  const int c = cg * 64 + lane;
  float r[5];
  const float* rp = rois + n * 5;
  #pragma unroll
  for (int i = 0; i < 5; ++i) r[i] = rp[i];
  int b = (int)r[0];
  b = min(max(b, 0), BB - 1);
  const float x1 = r[1] * 0.0625f - 0.5f;
  const float y1 = r[2] * 0.0625f - 0.5f;
  const float x2 = r[3] * 0.0625f - 0.5f;
  const float y2 = r[4] * 0.0625f - 0.5f;
  const float rw = x2 - x1, rh = y2 - y1;
  const float bw = rw * (1.0f / 7.0f), bh = rh * (1.0f / 7.0f);
  const float* fb = feat + (size_t)b * HW * NCH + c;
  for (int bin = w; bin < 49; bin += 4) {
    const int ph = bin / 7;
    const int pw = bin - ph * 7;
    float sw = x1, sh = y1;
    if (WITH_OFF) {
      sw += 0.1f * rw * offp[n * 98 + bin];
      sh += 0.1f * rh * offp[n * 98 + 49 + bin];
    }
    float acc = 0.f;
    #pragma unroll
    for (int s = 0; s < 4; ++s) {
      const int i = s >> 1, j = s & 1;
      const float y = sh + ((float)ph + 0.25f + 0.5f * (float)i) * bh;
      const float x = sw + ((float)pw + 0.25f + 0.5f * (float)j) * bw;
      const bool val = (y > -1.0f) && (y < (float)HH) && (x > -1.0f) && (x < (float)WW);
      float yc = fminf(fmaxf(y, 0.f), (float)(HH - 1));
      float xc = fminf(fmaxf(x, 0.f), (float)(WW - 1));
      int y0 = min(max((int)floorf(yc), 0), HH - 2);
      int x0 = min(max((int)floorf(xc), 0), WW - 2);
      const float ly = yc - (float)y0, lx = xc - (float)x0;
      const float hy = 1.f - ly, hx = 1.f - lx;
      if (val) {
        const float* p = fb + ((size_t)y0 * WW + x0) * NCH;
        acc += (hy * hx) * p[0] + (hy * lx) * p[NCH]
             + (ly * hx) * p[WW * NCH] + (ly * lx) * p[WW * NCH + NCH];
      }
    }
    obuf[lane * 49 + bin] = acc * 0.25f;
  }
  __syncthreads();
  const size_t base = (size_t)n * FDIM + (size_t)cg * (64 * 49);
  float* op = out + base;
  for (int i = threadIdx.x; i < 64 * 49; i += 256) {
    const float v = obuf[i];
    op[i] = v;
    if (SPLIT) {
      const u16 h = f2bf(v);
      ahi[base + i] = h;
      alo[base + i] = f2bf(v - bf2f(h));
    }
  }
}

// ------------- rescale head, 4-wave (proven) ---------------------------
__global__ __launch_bounds__(256) void rescale_rois_kernel(
    const float* __restrict__ flat, const float* __restrict__ w,
    const float* __restrict__ bsc, const float* __restrict__ rois,
    float* __restrict__ new_rois) {
  __shared__ float red[4];
  const int n = blockIdx.x;
  const int j = threadIdx.x >> 6;        // wave = output index 0..3
  const int lane = threadIdx.x & 63;
  const float* a = flat + (size_t)n * FDIM;
  const float* wj = w + (size_t)j * FDIM;
  float acc = 0.f;
  for (int k = lane * 8; k + 8 <= FDIM; k += 64 * 8) {
    f32x4 a0 = *(const f32x4*)(a + k);
    f32x4 a1 = *(const f32x4*)(a + k + 4);
    f32x4 w0 = *(const f32x4*)(wj + k);
    f32x4 w1 = *(const f32x4*)(wj + k + 4);
    float s = 0.f;
    #pragma unroll
    for (int e = 0; e < 4; ++e) s += a0[e] * w0[e];
    #pragma unroll
    for (int e = 0; e < 4; ++e) s += a1[e] * w1[e];
    acc += s;
  }
  #pragma unroll
  for (int d = 32; d > 0; d >>= 1)
    acc += __shfl_down(acc, d, 64);
  if (lane == 0) red[j] = acc;
  __syncthreads();
  if (threadIdx.x == 0) {
    float rr[5];
    const float* rp = rois + n * 5;
    #pragma unroll
    for (int i = 0; i < 5; ++i) rr[i] = rp[i];
    float sc[4];
    #pragma unroll
    for (int jj = 0; jj < 4; ++jj) {
      const float z = red[jj] + bsc[jj];
      sc[jj] = 1.0f + 0.5f / (1.0f + expf(-z));
    }
    const float cx = (rr[1] + rr[3]) * 0.5f + sc[0];
    const float cy = (rr[2] + rr[4]) * 0.5f + sc[1];
    const float nw = (rr[3] - rr[1]) * sc[2];
    const float nh = (rr[4] - rr[2]) * sc[3];
    float* o = new_rois + n * 5;
    o[0] = rr[0];
    o[1] = cx - 0.5f * nw;
    o[2] = cy - 0.5f * nh;
    o[3] = cx + 0.5f * nw;
    o[4] = cy + 0.5f * nh;
  }
}

// ---- split-K SPLIT-BF16 MFMA NT GEMM (round-8 structure, f32 A) -------
__global__ __launch_bounds__(512, 4) void gemm_mfma_sk(
    const float* __restrict__ A, const float* __restrict__ B,
    float* __restrict__ part, int M, int N, int Ns, int K, int kchunk) {
  __shared__ __align__(16) u16 Ah[64 * 32];
  __shared__ __align__(16) u16 Al[64 * 32];
  __shared__ __align__(16) u16 Bh[128 * 32];
  __shared__ __align__(16) u16 Bl[128 * 32];
  const int tid  = threadIdx.x;
  const int wave = tid >> 6;
  const int lane = tid & 63;
  const int q  = lane >> 4;
  const int rr = lane & 15;
  const int wr = wave >> 2;
  const int wc = wave & 3;
  const int m0 = blockIdx.y * 64;
  const int n0 = blockIdx.x * 128;
  const int s  = blockIdx.z;
  const int kb = s * kchunk, ke = kb + kchunk;

  const int srow  = tid >> 2;
  const int sslot = tid & 3;
  const int swz   = sslot ^ ((srow >> 1) & 3);
  const bool astage = tid < 256;
  u16* const a_sth = &Ah[srow * 32 + swz * 8];
  u16* const a_stl = &Al[srow * 32 + swz * 8];
  u16* const b_sth = &Bh[srow * 32 + swz * 8];
  u16* const b_stl = &Bl[srow * 32 + swz * 8];
  const float* Ap = A + (size_t)(m0 + (astage ? srow : 0)) * K + sslot * 8;
  const int  brow = n0 + srow;
  const bool bok  = brow < N;
  const float* Bp = B + (size_t)(bok ? brow : 0) * K + sslot * 8;

  const int rsw = q ^ ((rr >> 1) & 3);
  const u16* const a_rdh = &Ah[(wr * 32 + rr) * 32 + rsw * 8];
  const u16* const a_rdl = &Al[(wr * 32 + rr) * 32 + rsw * 8];
  const u16* const b_rdh = &Bh[(wc * 32 + rr) * 32 + rsw * 8];
  const u16* const b_rdl = &Bl[(wc * 32 + rr) * 32 + rsw * 8];

  f32x4 acc[2][2];
  #pragma unroll
  for (int mt = 0; mt < 2; ++mt)
    #pragma unroll
    for (int nt = 0; nt < 2; ++nt) acc[mt][nt] = (f32x4){0.f, 0.f, 0.f, 0.f};

  for (int k0 = kb; k0 < ke; k0 += 32) {
    f32x4 a0 = (f32x4){0.f, 0.f, 0.f, 0.f}, a1 = a0, b0 = a0, b1 = a0;
    if (astage) { a0 = *(const f32x4*)(Ap + k0); a1 = *(const f32x4*)(Ap + k0 + 4); }
    if (bok)    { b0 = *(const f32x4*)(Bp + k0); b1 = *(const f32x4*)(Bp + k0 + 4); }
    bf16x8 avh, avl, bvh, bvl;
    #pragma unroll
    for (int e = 0; e < 4; ++e) {
      const __bf16 h0 = (__bf16)a0[e], h1 = (__bf16)a1[e];
      avh[e] = h0; avh[e + 4] = h1;
      avl[e]     = (__bf16)(a0[e] - (float)h0);
      avl[e + 4] = (__bf16)(a1[e] - (float)h1);
      const __bf16 g0 = (__bf16)b0[e], g1 = (__bf16)b1[e];
      bvh[e] = g0; bvh[e + 4] = g1;
      bvl[e]     = (__bf16)(b0[e] - (float)g0);
      bvl[e + 4] = (__bf16)(b1[e] - (float)g1);
    }
    __syncthreads();
    if (astage) { *(bf16x8*)a_sth = avh; *(bf16x8*)a_stl = avl; }
    *(bf16x8*)b_sth = bvh;
    *(bf16x8*)b_stl = bvl;
    __syncthreads();
    bf16x8 ah[2], al[2], bh[2], bl[2];
    #pragma unroll
    for (int mt = 0; mt < 2; ++mt) {
      ah[mt] = *(const bf16x8*)(a_rdh + mt * 16 * 32);
      al[mt] = *(const bf16x8*)(a_rdl + mt * 16 * 32);
    }
    #pragma unroll
    for (int nt = 0; nt < 2; ++nt) {
      bh[nt] = *(const bf16x8*)(b_rdh + nt * 16 * 32);
      bl[nt] = *(const bf16x8*)(b_rdl + nt * 16 * 32);
    }
    #pragma unroll
    for (int mt = 0; mt < 2; ++mt)
      #pragma unroll
      for (int nt = 0; nt < 2; ++nt) {
        acc[mt][nt] = __builtin_amdgcn_mfma_f32_16x16x32_bf16(ah[mt], bh[nt], acc[mt][nt], 0, 0, 0);
        acc[mt][nt] = __builtin_amdgcn_mfma_f32_16x16x32_bf16(al[mt], bh[nt], acc[mt][nt], 0, 0, 0);
        acc[mt][nt] = __builtin_amdgcn_mfma_f32_16x16x32_bf16(ah[mt], bl[nt], acc[mt][nt], 0, 0, 0);
      }
  }

  float* pb = part + (size_t)s * M * Ns;
  #pragma unroll
  for (int mt = 0; mt < 2; ++mt)
    #pragma unroll
    for (int nt = 0; nt < 2; ++nt) {
      const int col = n0 + wc * 32 + nt * 16 + rr;
      #pragma unroll
      for (int i = 0; i < 4; ++i) {
        const int row = m0 + wr * 32 + mt * 16 + q * 4 + i;
        pb[(size_t)row * Ns + col] = acc[mt][nt][i];
      }
    }
}

// ---- pre-split-A GEMM, round-8 single-buffer 2-barrier structure ------
// A given as bf16 hi/lo u16 (pure s16x8 loads, no convert); B f32 with
// in-loop split (same order as gemm_mfma_sk -> same values). This reverts
// round-11's double-buffer restructure (A/B showed it cost 22%).
__global__ __launch_bounds__(512, 4) void gemm_ps(
    const u16* __restrict__ Ahi, const u16* __restrict__ Alo,
    const float* __restrict__ B,
    float* __restrict__ part, int M, int N, int Ns, int K, int kchunk) {
  __shared__ __align__(16) u16 Ah[64 * 32];
  __shared__ __align__(16) u16 Al[64 * 32];
  __shared__ __align__(16) u16 Bh[128 * 32];
  __shared__ __align__(16) u16 Bl[128 * 32];
  const int tid  = threadIdx.x;
  const int wave = tid >> 6;
  const int lane = tid & 63;
  const int q  = lane >> 4;
  const int rr = lane & 15;
  const int wr = wave >> 2;
  const int wc = wave & 3;
  const int m0 = blockIdx.y * 64;
  const int n0 = blockIdx.x * 128;
  const int s  = blockIdx.z;
  const int kb = s * kchunk, ke = kb + kchunk;

  const int srow  = tid >> 2;
  const int sslot = tid & 3;
  const int swz   = sslot ^ ((srow >> 1) & 3);
  const bool astage = tid < 256;
  u16* const a_sth = &Ah[srow * 32 + swz * 8];
  u16* const a_stl = &Al[srow * 32 + swz * 8];
  u16* const b_sth = &Bh[srow * 32 + swz * 8];
  u16* const b_stl = &Bl[srow * 32 + swz * 8];
  const u16* Aph = Ahi + (size_t)(m0 + (astage ? srow : 0)) * K + sslot * 8;
  const u16* Apl = Alo + (size_t)(m0 + (astage ? srow : 0)) * K + sslot * 8;
  const int  brow = n0 + srow;
  const bool bok  = brow < N;
  const float* Bp = B + (size_t)(bok ? brow : 0) * K + sslot * 8;

  const int rsw = q ^ ((rr >> 1) & 3);
  const u16* const a_rdh = &Ah[(wr * 32 + rr) * 32 + rsw * 8];
  const u16* const a_rdl = &Al[(wr * 32 + rr) * 32 + rsw * 8];
  const u16* const b_rdh = &Bh[(wc * 32 + rr) * 32 + rsw * 8];
  const u16* const b_rdl = &Bl[(wc * 32 + rr) * 32 + rsw * 8];

  f32x4 acc[2][2];
  #pragma unroll
  for (int mt = 0; mt < 2; ++mt)
    #pragma unroll
    for (int nt = 0; nt < 2; ++nt) acc[mt][nt] = (f32x4){0.f, 0.f, 0.f, 0.f};

  for (int k0 = kb; k0 < ke; k0 += 32) {
    s16x8 avh, avl;
    f32x4 b0 = (f32x4){0.f, 0.f, 0.f, 0.f}, b1 = b0;
    if (astage) { avh = *(const s16x8*)(Aph + k0); avl = *(const s16x8*)(Apl + k0); }
    if (bok)    { b0 = *(const f32x4*)(Bp + k0); b1 = *(const f32x4*)(Bp + k0 + 4); }
    bf16x8 bvh, bvl;
    #pragma unroll
    for (int e = 0; e < 4; ++e) {
      const __bf16 g0 = (__bf16)b0[e], g1 = (__bf16)b1[e];
      bvh[e] = g0; bvh[e + 4] = g1;
      bvl[e]     = (__bf16)(b0[e] - (float)g0);
      bvl[e + 4] = (__bf16)(b1[e] - (float)g1);
    }
    __syncthreads();
    if (astage) { *(s16x8*)a_sth = avh; *(s16x8*)a_stl = avl; }
    *(bf16x8*)b_sth = bvh;
    *(bf16x8*)b_stl = bvl;
    __syncthreads();
    bf16x8 ah[2], al[2], bh[2], bl[2];
    #pragma unroll
    for (int mt = 0; mt < 2; ++mt) {
      ah[mt] = *(const bf16x8*)(a_rdh + mt * 16 * 32);
      al[mt] = *(const bf16x8*)(a_rdl + mt * 16 * 32);
    }
    #pragma unroll
    for (int nt = 0; nt < 2; ++nt) {
      bh[nt] = *(const bf16x8*)(b_rdh + nt * 16 * 32);
      bl[nt] = *(const bf16x8*)(b_rdl + nt * 16 * 32);
    }
    #pragma unroll
    for (int mt = 0; mt < 2; ++mt)
      #pragma unroll
      for (int nt = 0; nt < 2; ++nt) {
        acc[mt][nt] = __builtin_amdgcn_mfma_f32_16x16x32_bf16(ah[mt], bh[nt], acc[mt][nt], 0, 0, 0);
        acc[mt][nt] = __builtin_amdgcn_mfma_f32_16x16x32_bf16(al[mt], bh[nt], acc[mt][nt], 0, 0, 0);
        acc[mt][nt] = __builtin_amdgcn_mfma_f32_16x16x32_bf16(ah[mt], bl[nt], acc[mt][nt], 0, 0, 0);
      }
  }

  float* pb = part + (size_t)s * M * Ns;
  #pragma unroll
  for (int mt = 0; mt < 2; ++mt)
    #pragma unroll
    for (int nt = 0; nt < 2; ++nt) {
      const int col = n0 + wc * 32 + nt * 16 + rr;
      #pragma unroll
      for (int i = 0; i < 4; ++i) {
        const int row = m0 + wr * 32 + mt * 16 + q * 4 + i;
        pb[(size_t)row * Ns + col] = acc[mt][nt][i];
      }
    }
}

// ---- reduce partials + bias (+relu) -> f32 out ------------------------
template<int RELU>
__global__ __launch_bounds__(256) void reduce_sk(
    const float* __restrict__ part, const float* __restrict__ bias,
    float* __restrict__ out, int M, int N, int Ns, int S) {
  const int idx = blockIdx.x * 256 + threadIdx.x;
  if (idx >= M * Ns) return;
  const int m = idx / Ns, n = idx - m * Ns;
  if (n >= N) return;
  float v = bias[n];
  for (int s = 0; s < S; ++s) v += part[(size_t)s * M * Ns + idx];
  if (RELU) v = fmaxf(v, 0.f);
  out[(size_t)m * N + n] = v;
}

// ---- reduce + relu -> pre-split bf16 hi/lo (feeds next GEMM's A side) --
__global__ __launch_bounds__(256) void reduce_sk_split(
    const float* __restrict__ part, const float* __restrict__ bias,
    u16* __restrict__ oh, u16* __restrict__ ol, int M, int N, int S) {
  const int idx = blockIdx.x * 256 + threadIdx.x;
  if (idx >= M * N) return;
  const int n = idx % N;
  float v = bias[n];
  for (int s = 0; s < S; ++s) v += part[(size_t)s * M * N + idx];
  v = fmaxf(v, 0.f);
  const u16 h = f2bf(v);
  oh[idx] = h;
  ol[idx] = f2bf(v - bf2f(h));
}

extern "C" void kernel_launch(void* const* d_in, const int* in_sizes, int n_in,
                              void* d_out, int out_size, void* d_ws, size_t ws_size,
                              hipStream_t stream) {
  const float* input  = (const float*)d_in[0];
  const float* rois   = (const float*)d_in[1];
  const float* resc_w = (const float*)d_in[2];
  const float* resc_b = (const float*)d_in[3];
  const float* w1     = (const float*)d_in[4];
  const float* b1     = (const float*)d_in[5];
  const float* w2     = (const float*)d_in[6];
  const float* b2     = (const float*)d_in[7];
  const float* w3     = (const float*)d_in[8];
  const float* b3     = (const float*)d_in[9];
  float* out = (float*)d_out;

  char* ws = (char*)d_ws;
  const size_t feat_t_bytes = (size_t)BB * HW * NCH * sizeof(float); // 59.375 MiB

  float* x_cls = out;
  float* x_reg = out + (size_t)NROIS * FDIM;

  // ---- tier-3 layout (pre-split + split-K 14), needs ~118.4 MiB ----
  const bool big3 = ws_size >= (((size_t)59 << 20) + feat_t_bytes);
  // ---- tier-2 layout (pre-split, S=8), needs ~106.4 MiB ----
  const bool big2 = ws_size >= (((size_t)47 << 20) + feat_t_bytes);
  // ---- tier-1 layout (round-8 f32 path), needs ~86.3 MiB ----
  const bool big = ws_size >= (((size_t)24 << 20) + feat_t_bytes);

  if (big3 || big2) {
    float* part;
    u16 *h1h, *h1l, *h2h, *h2l, *Ahi, *Alo;
    float *offbuf2, *nrois2, *feat_t2;
    int S1;
    if (big3) {
      part    = (float*)ws;                              // 28 MiB (S=14)
      h1h     = (u16*)(ws + ((size_t)28 << 20));
      h1l     = (u16*)(ws + ((size_t)29 << 20));
      h2h     = (u16*)(ws + ((size_t)30 << 20));
      h2l     = (u16*)(ws + ((size_t)31 << 20));
      offbuf2 = (float*)(ws + ((size_t)32 << 20));
      nrois2  = (float*)(ws + ((size_t)32 << 20) + 512 * 1024);
      Ahi     = (u16*)(ws + ((size_t)33 << 20));         // 12.25 MiB
      Alo     = (u16*)(ws + ((size_t)46 << 20));         // 12.25 MiB
      feat_t2 = (float*)(ws + ((size_t)59 << 20));       // 59.375 MiB
      S1 = 14;                                           // kchunk 896 = 28*32
    } else {
      part    = (float*)ws;                              // 16 MiB (S=8)
      h1h     = (u16*)(ws + ((size_t)16 << 20));
      h1l     = (u16*)(ws + ((size_t)17 << 20));
      h2h     = (u16*)(ws + ((size_t)18 << 20));
      h2l     = (u16*)(ws + ((size_t)19 << 20));
      offbuf2 = (float*)(ws + ((size_t)20 << 20));
      nrois2  = (float*)(ws + ((size_t)20 << 20) + 512 * 1024);
      Ahi     = (u16*)(ws + ((size_t)21 << 20));
      Alo     = (u16*)(ws + ((size_t)34 << 20));
      feat_t2 = (float*)(ws + ((size_t)47 << 20));
      S1 = 8;
    }

    nchw_to_nhwc<<<dim3(238, 4, 4), 256, 0, stream>>>(input, feat_t2);
    pool_nhwc_cg<0, 1><<<dim3(NROIS, 4), 256, 0, stream>>>(feat_t2, rois, nullptr, x_cls, Ahi, Alo);
    rescale_rois_kernel<<<NROIS, 256, 0, stream>>>(x_cls, resc_w, resc_b, rois, nrois2);

    // GEMM1: 512x1024x12544, split-K S1
    gemm_ps<<<dim3(8, 8, S1), 512, 0, stream>>>(Ahi, Alo, w1, part, NROIS, DFC, DFC, FDIM, FDIM / S1);
    reduce_sk_split<<<(NROIS * DFC + 255) / 256, 256, 0, stream>>>(part, b1, h1h, h1l, NROIS, DFC, S1);
    // GEMM2: 512x1024x1024, S=8
    gemm_ps<<<dim3(8, 8, 8), 512, 0, stream>>>(h1h, h1l, w2, part, NROIS, DFC, DFC, DFC, DFC / 8);
    reduce_sk_split<<<(NROIS * DFC + 255) / 256, 256, 0, stream>>>(part, b2, h2h, h2l, NROIS, DFC, 8);
    // GEMM3: 512x98x1024 (Ns=128 pad; B rows >= 98 staged as zeros)
    gemm_ps<<<dim3(1, 8, 8), 512, 0, stream>>>(h2h, h2l, w3, part, NROIS, 98, 128, DFC, DFC / 8);
    reduce_sk<0><<<(NROIS * 128 + 255) / 256, 256, 0, stream>>>(part, b3, offbuf2, NROIS, 98, 128, 8);

    pool_nhwc_cg<1, 0><<<dim3(NROIS, 4), 256, 0, stream>>>(feat_t2, nrois2, offbuf2, x_reg, nullptr, nullptr);
  } else if (big) {
    float* part   = (float*)ws;
    float* h1     = (float*)(ws + ((size_t)16 << 20));
    float* h2     = (float*)(ws + ((size_t)18 << 20));
    float* offbuf = (float*)(ws + ((size_t)22 << 20));
    float* nrois  = (float*)(ws + ((size_t)22 << 20) + 256 * 1024);
    float* feat_t = (float*)(ws + ((size_t)24 << 20));

    nchw_to_nhwc<<<dim3(238, 4, 4), 256, 0, stream>>>(input, feat_t);
    pool_nhwc_cg<0, 0><<<dim3(NROIS, 4), 256, 0, stream>>>(feat_t, rois, nullptr, x_cls, nullptr, nullptr);
    rescale_rois_kernel<<<NROIS, 256, 0, stream>>>(x_cls, resc_w, resc_b, rois, nrois);

    gemm_mfma_sk<<<dim3(8, 8, 8), 512, 0, stream>>>(x_cls, w1, part, NROIS, DFC, DFC, FDIM, FDIM / 8);
    reduce_sk<1><<<(NROIS * DFC + 255) / 256, 256, 0, stream>>>(part, b1, h1, NROIS, DFC, DFC, 8);
    gemm_mfma_sk<<<dim3(8, 8, 8), 512, 0, stream>>>(h1, w2, part, NROIS, DFC, DFC, DFC, DFC / 8);
    reduce_sk<1><<<(NROIS * DFC + 255) / 256, 256, 0, stream>>>(part, b2, h2, NROIS, DFC, DFC, 8);
    gemm_mfma_sk<<<dim3(1, 8, 8), 512, 0, stream>>>(h2, w3, part, NROIS, 98, 128, DFC, DFC / 8);
    reduce_sk<0><<<(NROIS * 128 + 255) / 256, 256, 0, stream>>>(part, b3, offbuf, NROIS, 98, 128, 8);

    pool_nhwc_cg<1, 0><<<dim3(NROIS, 4), 256, 0, stream>>>(feat_t, nrois, offbuf, x_reg, nullptr, nullptr);
  } else {
    float* part   = (float*)ws;
    float* h1     = (float*)(ws + ((size_t)16 << 20));
    float* h2     = (float*)(ws + ((size_t)18 << 20));
    float* offbuf = (float*)(ws + ((size_t)22 << 20));
    float* nrois  = (float*)(ws + ((size_t)22 << 20) + 256 * 1024);

    pool_nchw<0><<<NROIS, 256, 0, stream>>>(input, rois, nullptr, x_cls);
    rescale_rois_kernel<<<NROIS, 256, 0, stream>>>(x_cls, resc_w, resc_b, rois, nrois);
    gemm_mfma_sk<<<dim3(8, 8, 8), 512, 0, stream>>>(x_cls, w1, part, NROIS, DFC, DFC, FDIM, FDIM / 8);
    reduce_sk<1><<<(NROIS * DFC + 255) / 256, 256, 0, stream>>>(part, b1, h1, NROIS, DFC, DFC, 8);
    gemm_mfma_sk<<<dim3(8, 8, 8), 512, 0, stream>>>(h1, w2, part, NROIS, DFC, DFC, DFC, DFC / 8);
    reduce_sk<1><<<(NROIS * DFC + 255) / 256, 256, 0, stream>>>(part, b2, h2, NROIS, DFC, DFC, 8);
    gemm_mfma_sk<<<dim3(1, 8, 8), 512, 0, stream>>>(h2, w3, part, NROIS, 98, 128, DFC, DFC / 8);
    reduce_sk<0><<<(NROIS * 128 + 255) / 256, 256, 0, stream>>>(part, b3, offbuf, NROIS, 98, 128, 8);
    pool_nchw<1><<<NROIS, 256, 0, stream>>>(input, nrois, offbuf, x_reg);
  }
}

// Round 13
// 330.501 us; speedup vs baseline: 1.0953x; 1.0953x over previous
//
#include <hip/hip_runtime.h>
#include <math.h>

#define NCH 256
#define HH 100
#define WW 152
#define BB 4
#define NROIS 512
#define FDIM 12544   // 256*49
#define DFC 1024
#define HW 15200     // 100*152

typedef unsigned short u16;
typedef float f32x4 __attribute__((ext_vector_type(4)));
typedef short s16x8 __attribute__((ext_vector_type(8)));
typedef __bf16 bf16x8 __attribute__((ext_vector_type(8)));

// ---------------- deform roi pool, NCHW fallback (proven) --------------
template<int WITH_OFF>
__global__ __launch_bounds__(256) void pool_nchw(
    const float* __restrict__ feat, const float* __restrict__ rois,
    const float* __restrict__ offp, float* __restrict__ out) {
  const int n    = blockIdx.x;
  const int tid  = threadIdx.x;
  const int wave = tid >> 6;
  const int lane = tid & 63;
  float r[5];
  const float* rp = rois + n * 5;
  #pragma unroll
  for (int i = 0; i < 5; ++i) r[i] = rp[i];
  int b = (int)r[0];
  b = min(max(b, 0), BB - 1);
  const float x1 = r[1] * 0.0625f - 0.5f;
  const float y1 = r[2] * 0.0625f - 0.5f;
  const float x2 = r[3] * 0.0625f - 0.5f;
  const float y2 = r[4] * 0.0625f - 0.5f;
  const float rw = x2 - x1, rh = y2 - y1;
  const float bw = rw * (1.0f / 7.0f), bh = rh * (1.0f / 7.0f);
  const int bin = lane;
  const bool active = (bin < 49);
  const int ph = bin / 7;
  const int pw = bin - ph * 7;
  float sw = x1, sh = y1;
  if (WITH_OFF && active) {
    sw += 0.1f * rw * offp[n * 98 + bin];
    sh += 0.1f * rh * offp[n * 98 + 49 + bin];
  }
  int idx[4];
  float wt[4][4];
  bool val[4];
  #pragma unroll
  for (int s = 0; s < 4; ++s) {
    const int i = s >> 1, j = s & 1;
    const float y = sh + ((float)ph + 0.25f + 0.5f * (float)i) * bh;
    const float x = sw + ((float)pw + 0.25f + 0.5f * (float)j) * bw;
    val[s] = active && (y > -1.0f) && (y < (float)HH) && (x > -1.0f) && (x < (float)WW);
    float yc = fminf(fmaxf(y, 0.f), (float)(HH - 1));
    float xc = fminf(fmaxf(x, 0.f), (float)(WW - 1));
    int y0 = min(max((int)floorf(yc), 0), HH - 2);
    int x0 = min(max((int)floorf(xc), 0), WW - 2);
    const float ly = yc - (float)y0, lx = xc - (float)x0;
    const float hy = 1.f - ly, hx = 1.f - lx;
    idx[s] = y0 * WW + x0;
    wt[s][0] = hy * hx; wt[s][1] = hy * lx;
    wt[s][2] = ly * hx; wt[s][3] = ly * lx;
  }
  const float* fb = feat + (size_t)b * NCH * HW;
  float* op = out + (size_t)n * FDIM;
  for (int c = wave; c < NCH; c += 4) {
    const float* plane = fb + (size_t)c * HW;
    float acc = 0.f;
    #pragma unroll
    for (int s = 0; s < 4; ++s) {
      if (val[s]) {
        const float* p = plane + idx[s];
        acc += wt[s][0] * p[0] + wt[s][1] * p[1]
             + wt[s][2] * p[WW] + wt[s][3] * p[WW + 1];
      }
    }
    if (active) op[c * 49 + bin] = acc * 0.25f;
  }
}

// ------- NCHW -> NHWC transpose (64x64 LDS tile, both sides coalesced) --
__global__ __launch_bounds__(256) void nchw_to_nhwc(
    const float* __restrict__ in, float* __restrict__ outp) {
  __shared__ float tile[64][65];
  const int b  = blockIdx.z;
  const int c0 = blockIdx.y * 64;
  const int p0 = blockIdx.x * 64;
  const int tx = threadIdx.x & 63;
  const int ty = threadIdx.x >> 6;
  const float* ib = in + ((size_t)b * NCH + c0) * HW + p0;
  #pragma unroll
  for (int i = 0; i < 16; ++i) {
    const int r = ty + i * 4;                    // channel row 0..63
    tile[r][tx] = (p0 + tx < HW) ? ib[(size_t)r * HW + tx] : 0.f;
  }
  __syncthreads();
  float* ob = outp + ((size_t)b * HW + p0) * NCH + c0;
  #pragma unroll
  for (int i = 0; i < 16; ++i) {
    const int pr = ty + i * 4;                   // position row 0..63
    if (p0 + pr < HW) ob[(size_t)pr * NCH + tx] = tile[tx][pr];
  }
}

// ------ deform roi pool on NHWC, channel-group split + LDS store -------
// (round-8 proven, SPLIT path removed: pre-split-A refuted in r11/r12)
template<int WITH_OFF>
__global__ __launch_bounds__(256) void pool_nhwc_cg(
    const float* __restrict__ feat, const float* __restrict__ rois,
    const float* __restrict__ offp, float* __restrict__ out) {
  __shared__ float obuf[64 * 49];
  const int n  = blockIdx.x;
  const int cg = blockIdx.y;               // channel group 0..3
  const int w    = threadIdx.x >> 6;       // wave 0..3
  const int lane = threadIdx.x & 63;       // c_local
  const int c = cg * 64 + lane;
  float r[5];
  const float* rp = rois + n * 5;
  #pragma unroll
  for (int i = 0; i < 5; ++i) r[i] = rp[i];
  int b = (int)r[0];
  b = min(max(b, 0), BB - 1);
  const float x1 = r[1] * 0.0625f - 0.5f;
  const float y1 = r[2] * 0.0625f - 0.5f;
  const float x2 = r[3] * 0.0625f - 0.5f;
  const float y2 = r[4] * 0.0625f - 0.5f;
  const float rw = x2 - x1, rh = y2 - y1;
  const float bw = rw * (1.0f / 7.0f), bh = rh * (1.0f / 7.0f);
  const float* fb = feat + (size_t)b * HW * NCH + c;
  for (int bin = w; bin < 49; bin += 4) {
    const int ph = bin / 7;
    const int pw = bin - ph * 7;
    float sw = x1, sh = y1;
    if (WITH_OFF) {
      sw += 0.1f * rw * offp[n * 98 + bin];
      sh += 0.1f * rh * offp[n * 98 + 49 + bin];
    }
    float acc = 0.f;
    #pragma unroll
    for (int s = 0; s < 4; ++s) {
      const int i = s >> 1, j = s & 1;
      const float y = sh + ((float)ph + 0.25f + 0.5f * (float)i) * bh;
      const float x = sw + ((float)pw + 0.25f + 0.5f * (float)j) * bw;
      const bool val = (y > -1.0f) && (y < (float)HH) && (x > -1.0f) && (x < (float)WW);
      float yc = fminf(fmaxf(y, 0.f), (float)(HH - 1));
      float xc = fminf(fmaxf(x, 0.f), (float)(WW - 1));
      int y0 = min(max((int)floorf(yc), 0), HH - 2);
      int x0 = min(max((int)floorf(xc), 0), WW - 2);
      const float ly = yc - (float)y0, lx = xc - (float)x0;
      const float hy = 1.f - ly, hx = 1.f - lx;
      if (val) {
        const float* p = fb + ((size_t)y0 * WW + x0) * NCH;
        acc += (hy * hx) * p[0] + (hy * lx) * p[NCH]
             + (ly * hx) * p[WW * NCH] + (ly * lx) * p[WW * NCH + NCH];
      }
    }
    obuf[lane * 49 + bin] = acc * 0.25f;
  }
  __syncthreads();
  float* op = out + (size_t)n * FDIM + (size_t)cg * (64 * 49);
  for (int i = threadIdx.x; i < 64 * 49; i += 256) op[i] = obuf[i];
}

// ------------- rescale head, 4-wave (proven) ---------------------------
__global__ __launch_bounds__(256) void rescale_rois_kernel(
    const float* __restrict__ flat, const float* __restrict__ w,
    const float* __restrict__ bsc, const float* __restrict__ rois,
    float* __restrict__ new_rois) {
  __shared__ float red[4];
  const int n = blockIdx.x;
  const int j = threadIdx.x >> 6;        // wave = output index 0..3
  const int lane = threadIdx.x & 63;
  const float* a = flat + (size_t)n * FDIM;
  const float* wj = w + (size_t)j * FDIM;
  float acc = 0.f;
  for (int k = lane * 8; k + 8 <= FDIM; k += 64 * 8) {
    f32x4 a0 = *(const f32x4*)(a + k);
    f32x4 a1 = *(const f32x4*)(a + k + 4);
    f32x4 w0 = *(const f32x4*)(wj + k);
    f32x4 w1 = *(const f32x4*)(wj + k + 4);
    float s = 0.f;
    #pragma unroll
    for (int e = 0; e < 4; ++e) s += a0[e] * w0[e];
    #pragma unroll
    for (int e = 0; e < 4; ++e) s += a1[e] * w1[e];
    acc += s;
  }
  #pragma unroll
  for (int d = 32; d > 0; d >>= 1)
    acc += __shfl_down(acc, d, 64);
  if (lane == 0) red[j] = acc;
  __syncthreads();
  if (threadIdx.x == 0) {
    float rr[5];
    const float* rp = rois + n * 5;
    #pragma unroll
    for (int i = 0; i < 5; ++i) rr[i] = rp[i];
    float sc[4];
    #pragma unroll
    for (int jj = 0; jj < 4; ++jj) {
      const float z = red[jj] + bsc[jj];
      sc[jj] = 1.0f + 0.5f / (1.0f + expf(-z));
    }
    const float cx = (rr[1] + rr[3]) * 0.5f + sc[0];
    const float cy = (rr[2] + rr[4]) * 0.5f + sc[1];
    const float nw = (rr[3] - rr[1]) * sc[2];
    const float nh = (rr[4] - rr[2]) * sc[3];
    float* o = new_rois + n * 5;
    o[0] = rr[0];
    o[1] = cx - 0.5f * nw;
    o[2] = cy - 0.5f * nh;
    o[3] = cx + 0.5f * nw;
    o[4] = cy + 0.5f * nh;
  }
}

// ---- split-K SPLIT-BF16 MFMA NT GEMM, 64x128 tile (round-8, proven) ---
__global__ __launch_bounds__(512, 4) void gemm_mfma_sk(
    const float* __restrict__ A, const float* __restrict__ B,
    float* __restrict__ part, int M, int N, int Ns, int K, int kchunk) {
  __shared__ __align__(16) u16 Ah[64 * 32];
  __shared__ __align__(16) u16 Al[64 * 32];
  __shared__ __align__(16) u16 Bh[128 * 32];
  __shared__ __align__(16) u16 Bl[128 * 32];
  const int tid  = threadIdx.x;
  const int wave = tid >> 6;
  const int lane = tid & 63;
  const int q  = lane >> 4;
  const int rr = lane & 15;
  const int wr = wave >> 2;
  const int wc = wave & 3;
  const int m0 = blockIdx.y * 64;
  const int n0 = blockIdx.x * 128;
  const int s  = blockIdx.z;
  const int kb = s * kchunk, ke = kb + kchunk;

  const int srow  = tid >> 2;
  const int sslot = tid & 3;
  const int swz   = sslot ^ ((srow >> 1) & 3);
  const bool astage = tid < 256;
  u16* const a_sth = &Ah[srow * 32 + swz * 8];
  u16* const a_stl = &Al[srow * 32 + swz * 8];
  u16* const b_sth = &Bh[srow * 32 + swz * 8];
  u16* const b_stl = &Bl[srow * 32 + swz * 8];
  const float* Ap = A + (size_t)(m0 + (astage ? srow : 0)) * K + sslot * 8;
  const int  brow = n0 + srow;
  const bool bok  = brow < N;
  const float* Bp = B + (size_t)(bok ? brow : 0) * K + sslot * 8;

  const int rsw = q ^ ((rr >> 1) & 3);
  const u16* const a_rdh = &Ah[(wr * 32 + rr) * 32 + rsw * 8];
  const u16* const a_rdl = &Al[(wr * 32 + rr) * 32 + rsw * 8];
  const u16* const b_rdh = &Bh[(wc * 32 + rr) * 32 + rsw * 8];
  const u16* const b_rdl = &Bl[(wc * 32 + rr) * 32 + rsw * 8];

  f32x4 acc[2][2];
  #pragma unroll
  for (int mt = 0; mt < 2; ++mt)
    #pragma unroll
    for (int nt = 0; nt < 2; ++nt) acc[mt][nt] = (f32x4){0.f, 0.f, 0.f, 0.f};

  for (int k0 = kb; k0 < ke; k0 += 32) {
    f32x4 a0 = (f32x4){0.f, 0.f, 0.f, 0.f}, a1 = a0, b0 = a0, b1 = a0;
    if (astage) { a0 = *(const f32x4*)(Ap + k0); a1 = *(const f32x4*)(Ap + k0 + 4); }
    if (bok)    { b0 = *(const f32x4*)(Bp + k0); b1 = *(const f32x4*)(Bp + k0 + 4); }
    bf16x8 avh, avl, bvh, bvl;
    #pragma unroll
    for (int e = 0; e < 4; ++e) {
      const __bf16 h0 = (__bf16)a0[e], h1 = (__bf16)a1[e];
      avh[e] = h0; avh[e + 4] = h1;
      avl[e]     = (__bf16)(a0[e] - (float)h0);
      avl[e + 4] = (__bf16)(a1[e] - (float)h1);
      const __bf16 g0 = (__bf16)b0[e], g1 = (__bf16)b1[e];
      bvh[e] = g0; bvh[e + 4] = g1;
      bvl[e]     = (__bf16)(b0[e] - (float)g0);
      bvl[e + 4] = (__bf16)(b1[e] - (float)g1);
    }
    __syncthreads();
    if (astage) { *(bf16x8*)a_sth = avh; *(bf16x8*)a_stl = avl; }
    *(bf16x8*)b_sth = bvh;
    *(bf16x8*)b_stl = bvl;
    __syncthreads();
    bf16x8 ah[2], al[2], bh[2], bl[2];
    #pragma unroll
    for (int mt = 0; mt < 2; ++mt) {
      ah[mt] = *(const bf16x8*)(a_rdh + mt * 16 * 32);
      al[mt] = *(const bf16x8*)(a_rdl + mt * 16 * 32);
    }
    #pragma unroll
    for (int nt = 0; nt < 2; ++nt) {
      bh[nt] = *(const bf16x8*)(b_rdh + nt * 16 * 32);
      bl[nt] = *(const bf16x8*)(b_rdl + nt * 16 * 32);
    }
    #pragma unroll
    for (int mt = 0; mt < 2; ++mt)
      #pragma unroll
      for (int nt = 0; nt < 2; ++nt) {
        acc[mt][nt] = __builtin_amdgcn_mfma_f32_16x16x32_bf16(ah[mt], bh[nt], acc[mt][nt], 0, 0, 0);
        acc[mt][nt] = __builtin_amdgcn_mfma_f32_16x16x32_bf16(al[mt], bh[nt], acc[mt][nt], 0, 0, 0);
        acc[mt][nt] = __builtin_amdgcn_mfma_f32_16x16x32_bf16(ah[mt], bl[nt], acc[mt][nt], 0, 0, 0);
      }
  }

  float* pb = part + (size_t)s * M * Ns;
  #pragma unroll
  for (int mt = 0; mt < 2; ++mt)
    #pragma unroll
    for (int nt = 0; nt < 2; ++nt) {
      const int col = n0 + wc * 32 + nt * 16 + rr;
      #pragma unroll
      for (int i = 0; i < 4; ++i) {
        const int row = m0 + wr * 32 + mt * 16 + q * 4 + i;
        pb[(size_t)row * Ns + col] = acc[mt][nt][i];
      }
    }
}

// ---- 128x128-tile variant: same single-buffer 2-barrier structure, ----
// same swizzle involution, same D-map. Wave tile 64x32 -> 24 MFMA per
// wave per k-step (2x the 64x128 kernel) amortizing the barrier drain.
// All 512 threads stage both A (128 rows) and B (128 rows). M mult 128.
__global__ __launch_bounds__(512, 4) void gemm_mfma_sk128(
    const float* __restrict__ A, const float* __restrict__ B,
    float* __restrict__ part, int M, int N, int Ns, int K, int kchunk) {
  __shared__ __align__(16) u16 Ah[128 * 32];
  __shared__ __align__(16) u16 Al[128 * 32];
  __shared__ __align__(16) u16 Bh[128 * 32];
  __shared__ __align__(16) u16 Bl[128 * 32];
  const int tid  = threadIdx.x;
  const int wave = tid >> 6;
  const int lane = tid & 63;
  const int q  = lane >> 4;
  const int rr = lane & 15;
  const int wr = wave >> 2;        // 0..1 : 64 M-rows each
  const int wc = wave & 3;         // 0..3 : 32 N-cols each
  const int m0 = blockIdx.y * 128;
  const int n0 = blockIdx.x * 128;
  const int s  = blockIdx.z;
  const int kb = s * kchunk, ke = kb + kchunk;

  const int srow  = tid >> 2;      // 0..127
  const int sslot = tid & 3;
  const int swz   = sslot ^ ((srow >> 1) & 3);
  u16* const a_sth = &Ah[srow * 32 + swz * 8];
  u16* const a_stl = &Al[srow * 32 + swz * 8];
  u16* const b_sth = &Bh[srow * 32 + swz * 8];
  u16* const b_stl = &Bl[srow * 32 + swz * 8];
  const float* Ap = A + (size_t)(m0 + srow) * K + sslot * 8;
  const int  brow = n0 + srow;
  const bool bok  = brow < N;
  const float* Bp = B + (size_t)(bok ? brow : 0) * K + sslot * 8;

  // fragment reads: row bases 16-aligned -> (row>>1)&3 == (rr>>1)&3
  const int rsw = q ^ ((rr >> 1) & 3);
  const u16* const a_rdh = &Ah[(wr * 64 + rr) * 32 + rsw * 8];
  const u16* const a_rdl = &Al[(wr * 64 + rr) * 32 + rsw * 8];
  const u16* const b_rdh = &Bh[(wc * 32 + rr) * 32 + rsw * 8];
  const u16* const b_rdl = &Bl[(wc * 32 + rr) * 32 + rsw * 8];

  f32x4 acc[4][2];
  #pragma unroll
  for (int mt = 0; mt < 4; ++mt)
    #pragma unroll
    for (int nt = 0; nt < 2; ++nt) acc[mt][nt] = (f32x4){0.f, 0.f, 0.f, 0.f};

  for (int k0 = kb; k0 < ke; k0 += 32) {
    f32x4 a0 = *(const f32x4*)(Ap + k0);
    f32x4 a1 = *(const f32x4*)(Ap + k0 + 4);
    f32x4 b0 = (f32x4){0.f, 0.f, 0.f, 0.f}, b1 = b0;
    if (bok) { b0 = *(const f32x4*)(Bp + k0); b1 = *(const f32x4*)(Bp + k0 + 4); }
    bf16x8 avh, avl, bvh, bvl;
    #pragma unroll
    for (int e = 0; e < 4; ++e) {
      const __bf16 h0 = (__bf16)a0[e], h1 = (__bf16)a1[e];
      avh[e] = h0; avh[e + 4] = h1;
      avl[e]     = (__bf16)(a0[e] - (float)h0);
      avl[e + 4] = (__bf16)(a1[e] - (float)h1);
      const __bf16 g0 = (__bf16)b0[e], g1 = (__bf16)b1[e];
      bvh[e] = g0; bvh[e + 4] = g1;
      bvl[e]     = (__bf16)(b0[e] - (float)g0);
      bvl[e + 4] = (__bf16)(b1[e] - (float)g1);
    }
    __syncthreads();
    *(bf16x8*)a_sth = avh;
    *(bf16x8*)a_stl = avl;
    *(bf16x8*)b_sth = bvh;
    *(bf16x8*)b_stl = bvl;
    __syncthreads();
    bf16x8 bh[2], bl[2];
    #pragma unroll
    for (int nt = 0; nt < 2; ++nt) {
      bh[nt] = *(const bf16x8*)(b_rdh + nt * 16 * 32);
      bl[nt] = *(const bf16x8*)(b_rdl + nt * 16 * 32);
    }
    #pragma unroll
    for (int mt = 0; mt < 4; ++mt) {
      const bf16x8 ah = *(const bf16x8*)(a_rdh + mt * 16 * 32);
      const bf16x8 al = *(const bf16x8*)(a_rdl + mt * 16 * 32);
      #pragma unroll
      for (int nt = 0; nt < 2; ++nt) {
        acc[mt][nt] = __builtin_amdgcn_mfma_f32_16x16x32_bf16(ah, bh[nt], acc[mt][nt], 0, 0, 0);
        acc[mt][nt] = __builtin_amdgcn_mfma_f32_16x16x32_bf16(al, bh[nt], acc[mt][nt], 0, 0, 0);
        acc[mt][nt] = __builtin_amdgcn_mfma_f32_16x16x32_bf16(ah, bl[nt], acc[mt][nt], 0, 0, 0);
      }
    }
  }

  float* pb = part + (size_t)s * M * Ns;
  #pragma unroll
  for (int mt = 0; mt < 4; ++mt)
    #pragma unroll
    for (int nt = 0; nt < 2; ++nt) {
      const int col = n0 + wc * 32 + nt * 16 + rr;
      #pragma unroll
      for (int i = 0; i < 4; ++i) {
        const int row = m0 + wr * 64 + mt * 16 + q * 4 + i;
        pb[(size_t)row * Ns + col] = acc[mt][nt][i];
      }
    }
}

// ---- reduce partials + bias (+relu) -> f32 out ------------------------
template<int RELU>
__global__ __launch_bounds__(256) void reduce_sk(
    const float* __restrict__ part, const float* __restrict__ bias,
    float* __restrict__ out, int M, int N, int Ns, int S) {
  const int idx = blockIdx.x * 256 + threadIdx.x;
  if (idx >= M * Ns) return;
  const int m = idx / Ns, n = idx - m * Ns;
  if (n >= N) return;
  float v = bias[n];
  for (int s = 0; s < S; ++s) v += part[(size_t)s * M * Ns + idx];
  if (RELU) v = fmaxf(v, 0.f);
  out[(size_t)m * N + n] = v;
}

extern "C" void kernel_launch(void* const* d_in, const int* in_sizes, int n_in,
                              void* d_out, int out_size, void* d_ws, size_t ws_size,
                              hipStream_t stream) {
  const float* input  = (const float*)d_in[0];
  const float* rois   = (const float*)d_in[1];
  const float* resc_w = (const float*)d_in[2];
  const float* resc_b = (const float*)d_in[3];
  const float* w1     = (const float*)d_in[4];
  const float* b1     = (const float*)d_in[5];
  const float* w2     = (const float*)d_in[6];
  const float* b2     = (const float*)d_in[7];
  const float* w3     = (const float*)d_in[8];
  const float* b3     = (const float*)d_in[9];
  float* out = (float*)d_out;

  char* ws = (char*)d_ws;
  const size_t feat_t_bytes = (size_t)BB * HW * NCH * sizeof(float); // 59.375 MiB

  float* x_cls = out;
  float* x_reg = out + (size_t)NROIS * FDIM;

  // tier-A: 128^2-tile GEMM1 S=14 (part 28 MiB), needs ~92.4 MiB
  const bool bigA = ws_size >= (((size_t)33 << 20) + feat_t_bytes);
  // tier-B: round-8 exact (part 16 MiB), needs ~86.3 MiB
  const bool bigB = ws_size >= (((size_t)24 << 20) + feat_t_bytes);

  if (bigA) {
    float* part   = (float*)ws;                                  // 28 MiB (S=14)
    float* h1     = (float*)(ws + ((size_t)28 << 20));           // 2 MiB
    float* h2     = (float*)(ws + ((size_t)30 << 20));           // 2 MiB
    float* offbuf = (float*)(ws + ((size_t)32 << 20));           // 256 KiB
    float* nrois  = (float*)(ws + ((size_t)32 << 20) + 512 * 1024);
    float* feat_t = (float*)(ws + ((size_t)33 << 20));           // 59.375 MiB

    nchw_to_nhwc<<<dim3(238, 4, 4), 256, 0, stream>>>(input, feat_t);
    pool_nhwc_cg<0><<<dim3(NROIS, 4), 256, 0, stream>>>(feat_t, rois, nullptr, x_cls);
    rescale_rois_kernel<<<NROIS, 256, 0, stream>>>(x_cls, resc_w, resc_b, rois, nrois);

    // GEMM1: 512x1024x12544, 128^2 tile, S=14 (kchunk 896 = 28*32)
    gemm_mfma_sk128<<<dim3(8, 4, 14), 512, 0, stream>>>(x_cls, w1, part, NROIS, DFC, DFC, FDIM, FDIM / 14);
    reduce_sk<1><<<(NROIS * DFC + 255) / 256, 256, 0, stream>>>(part, b1, h1, NROIS, DFC, DFC, 14);
    // GEMM2: 512x1024x1024 (round-8 64x128, S=8)
    gemm_mfma_sk<<<dim3(8, 8, 8), 512, 0, stream>>>(h1, w2, part, NROIS, DFC, DFC, DFC, DFC / 8);
    reduce_sk<1><<<(NROIS * DFC + 255) / 256, 256, 0, stream>>>(part, b2, h2, NROIS, DFC, DFC, 8);
    // GEMM3: 512x98x1024 (Ns=128 pad; B rows >= 98 staged as zeros)
    gemm_mfma_sk<<<dim3(1, 8, 8), 512, 0, stream>>>(h2, w3, part, NROIS, 98, 128, DFC, DFC / 8);
    reduce_sk<0><<<(NROIS * 128 + 255) / 256, 256, 0, stream>>>(part, b3, offbuf, NROIS, 98, 128, 8);

    pool_nhwc_cg<1><<<dim3(NROIS, 4), 256, 0, stream>>>(feat_t, nrois, offbuf, x_reg);
  } else if (bigB) {
    float* part   = (float*)ws;
    float* h1     = (float*)(ws + ((size_t)16 << 20));
    float* h2     = (float*)(ws + ((size_t)18 << 20));
    float* offbuf = (float*)(ws + ((size_t)22 << 20));
    float* nrois  = (float*)(ws + ((size_t)22 << 20) + 256 * 1024);
    float* feat_t = (float*)(ws + ((size_t)24 << 20));

    nchw_to_nhwc<<<dim3(238, 4, 4), 256, 0, stream>>>(input, feat_t);
    pool_nhwc_cg<0><<<dim3(NROIS, 4), 256, 0, stream>>>(feat_t, rois, nullptr, x_cls);
    rescale_rois_kernel<<<NROIS, 256, 0, stream>>>(x_cls, resc_w, resc_b, rois, nrois);

    gemm_mfma_sk<<<dim3(8, 8, 8), 512, 0, stream>>>(x_cls, w1, part, NROIS, DFC, DFC, FDIM, FDIM / 8);
    reduce_sk<1><<<(NROIS * DFC + 255) / 256, 256, 0, stream>>>(part, b1, h1, NROIS, DFC, DFC, 8);
    gemm_mfma_sk<<<dim3(8, 8, 8), 512, 0, stream>>>(h1, w2, part, NROIS, DFC, DFC, DFC, DFC / 8);
    reduce_sk<1><<<(NROIS * DFC + 255) / 256, 256, 0, stream>>>(part, b2, h2, NROIS, DFC, DFC, 8);
    gemm_mfma_sk<<<dim3(1, 8, 8), 512, 0, stream>>>(h2, w3, part, NROIS, 98, 128, DFC, DFC / 8);
    reduce_sk<0><<<(NROIS * 128 + 255) / 256, 256, 0, stream>>>(part, b3, offbuf, NROIS, 98, 128, 8);

    pool_nhwc_cg<1><<<dim3(NROIS, 4), 256, 0, stream>>>(feat_t, nrois, offbuf, x_reg);
  } else {
    float* part   = (float*)ws;
    float* h1     = (float*)(ws + ((size_t)16 << 20));
    float* h2     = (float*)(ws + ((size_t)18 << 20));
    float* offbuf = (float*)(ws + ((size_t)22 << 20));
    float* nrois  = (float*)(ws + ((size_t)22 << 20) + 256 * 1024);

    pool_nchw<0><<<NROIS, 256, 0, stream>>>(input, rois, nullptr, x_cls);
    rescale_rois_kernel<<<NROIS, 256, 0, stream>>>(x_cls, resc_w, resc_b, rois, nrois);
    gemm_mfma_sk<<<dim3(8, 8, 8), 512, 0, stream>>>(x_cls, w1, part, NROIS, DFC, DFC, FDIM, FDIM / 8);
    reduce_sk<1><<<(NROIS * DFC + 255) / 256, 256, 0, stream>>>(part, b1, h1, NROIS, DFC, DFC, 8);
    gemm_mfma_sk<<<dim3(8, 8, 8), 512, 0, stream>>>(h1, w2, part, NROIS, DFC, DFC, DFC, DFC / 8);
    reduce_sk<1><<<(NROIS * DFC + 255) / 256, 256, 0, stream>>>(part, b2, h2, NROIS, DFC, DFC, 8);
    gemm_mfma_sk<<<dim3(1, 8, 8), 512, 0, stream>>>(h2, w3, part, NROIS, 98, 128, DFC, DFC / 8);
    reduce_sk<0><<<(NROIS * 128 + 255) / 256, 256, 0, stream>>>(part, b3, offbuf, NROIS, 98, 128, 8);
    pool_nchw<1><<<NROIS, 256, 0, stream>>>(input, nrois, offbuf, x_reg);
  }
}